// Round 3
// baseline (138.728 us; speedup 1.0000x reference)
//
#include <hip/hip_runtime.h>
#include <hip/hip_bf16.h>

// Fused 34->128->128->1 MLP, bf16 MFMA, transposed GEMMs.
// R13 = R12 structure with the register-allocator contract PINNED.
// R12 post-mortem: __launch_bounds__(256,4) sets only MIN waves/EU; the
// allocator chased the 8-waves/EU rung (64-reg cap) and spilled 14.5MB/
// dispatch (WRITE_SIZE 18.4MB vs 3.9MB out-only) -> 76.7us, worse than
// R10's 63us. Fix: amdgpu_waves_per_eu(4,4) pins BOTH ends -> budget 128,
// no incentive to shrink. Hand-counted peak liveness ~120 < 128.
// R10 lesson (revised): its 68-VGPR fit hid weights in AGPRs (unified
// file) -> accvgpr read/write traffic inflated VALUBusy; with a real
// 128-reg budget the weights live in arch VGPRs.
// Kept from R11/R12 (all verified correct, absmax unchanged):
//  - clamp fused into v_cvt_pk_bf16_f32 (pk2c) -- kills 64 med3/wave-tile
//  - L2 as MFMA (W2 in A row 0) -- kills 64-op VALU dot + 16-row reduce
//  - biases ride first MFMA C operand -- kills 64 acc-init movs
//  - PART aliased into A0 cols 64..71 -> LDS 26624B, 4 blocks = 104KB/CU
//  - no own[]: L1 kk=0 reads H0 like kk>=1 (+4 ds_read_b128, -16 VGPRs)
//  - w1r rotation: literal register indices in L1 (anti-scratch rule)
// R8a recap: physical hidden h = nq*32 + q*8 + hb*4 + r at MFMA position
// (nq,hb,q,r); L0 C/D frag == L1 B frag layout.
// Evidence trail: R6 -ds_bpermute 115->80; R7 transpose 80->72; R9-R12
// spill lessons (WRITE_SIZE is the spill tell; launch_bounds min-only).

using bf16x8 = __attribute__((ext_vector_type(8))) short;   // 8 bf16 = 4 VGPRs
using f32x4  = __attribute__((ext_vector_type(4))) float;   // MFMA C/D

#define NPTS    1000000
#define NUMEMB  6572
#define HID     128
#define M_IT    64          // points per block-iteration
#define A0S     72          // A0 row stride in bf16 (144B, 16B-aligned rows)
#define H0S     136         // H0 row stride in bf16 (272B, 16B-aligned rows)
#define TILES   (NPTS / M_IT)   // 15625 exactly
#define NBLOCKS 1024        // 4 blocks/CU on 256 CUs (LDS 26624*4 = 104KB)

__device__ __forceinline__ unsigned short bf16r(float f) {
    unsigned u;
    __builtin_memcpy(&u, &f, 4);
    u = (u + 0x7fffu + ((u >> 16) & 1u)) >> 16;
    return (unsigned short)u;
}
__device__ __forceinline__ unsigned pk2(float a, float b) {
    // packed RNE f32x2 -> bf16x2 (v_cvt_pk_bf16_f32 on gfx950)
    float2 f2; f2.x = a; f2.y = b;
    __hip_bfloat162 h = __float22bfloat162_rn(f2);
    unsigned u;
    __builtin_memcpy(&u, &h, 4);
    return u;
}
__device__ __forceinline__ unsigned pk2c(float a, float b) {
    // packed cvt with VOP3 clamp: result clamped to [0,1] — fuses clamp01
    unsigned r;
    asm("v_cvt_pk_bf16_f32 %0, %1, %2 clamp" : "=v"(r) : "v"(a), "v"(b));
    return r;
}

__global__ __attribute__((amdgpu_flat_work_group_size(256, 256),
                          amdgpu_waves_per_eu(4, 4)))
void mlp_fused(const float* __restrict__ x,
               const float* __restrict__ emb,
               const float* __restrict__ em_table,
               const float* __restrict__ W0, const float* __restrict__ b0,
               const float* __restrict__ W1, const float* __restrict__ b1,
               const float* __restrict__ W2, const float* __restrict__ b2,
               float* __restrict__ out)
{
    __shared__ __align__(16) unsigned short A0[M_IT * A0S];  // bf16 [pt][in]
    __shared__ __align__(16) unsigned short H0[M_IT * H0S];  // bf16 [pt][hperm]
    // PART[p][w] aliased into A0 bytes p*144 + 128 + w*4 (cols 64..71,
    // never accessed as A0: reads span cols <=63, writes cols <=33).

    const int tid  = threadIdx.x;
    const int lane = tid & 63;
    const int nq   = tid >> 6;   // wave's physical hidden block [nq*32,+32)
    const int q    = lane >> 4;  // quad within wave
    const int cl   = lane & 15;
    const int p    = tid >> 2;   // staging: point within tile
    const int s    = tid & 3;    // staging: 8-dim segment of embedding

    // zero A0 once (cols 34..63 stay zero forever; build overwrites 0..33)
    for (int i = tid; i < M_IT * A0S; i += 256) A0[i] = 0;

    // ---- one-time: weight A-fragments (permuted cols) into registers ----
    // A-frag lane (q,cl) holds A[m=cl][k=q*8+e]. Permuted physical hidden
    // for column m within block (nq,hb): h = nq*32 + (m>>2)*8 + hb*4 + (m&3).
    const int hcol = nq * 32 + (cl >> 2) * 8 + (cl & 3);  // + hb*4
    // W0 logical row k: k<32 -> em row 2+k ; k==32 -> x row 0 ; k==33 -> 1.
    bf16x8 w0t[2][2];   // [hb][kt]
    for (int hb = 0; hb < 2; ++hb)
        for (int kt = 0; kt < 2; ++kt) {
            const int col = hcol + hb * 4;
            bf16x8 v;
            #pragma unroll
            for (int e = 0; e < 8; ++e) {
                const int k = kt * 32 + q * 8 + e;
                float val = 0.f;
                if (k < 32)       val = W0[(2 + k) * HID + col];
                else if (k == 32) val = W0[0 * HID + col];
                else if (k == 33) val = W0[1 * HID + col];
                v[e] = (short)bf16r(val);
            }
            w0t[hb][kt] = v;
        }

    // W1 ROTATED: w1r[hb][kk] holds rows kphys = ((nq+kk)&3)*32 + q*8 + e
    bf16x8 w1r[2][4];   // [hb][kk]
    for (int hb = 0; hb < 2; ++hb)
        for (int kk = 0; kk < 4; ++kk) {
            const int kt  = (nq + kk) & 3;
            const int col = hcol + hb * 4;
            bf16x8 v;
            #pragma unroll
            for (int e = 0; e < 8; ++e) {
                const int k = kt * 32 + q * 8 + e;
                v[e] = (short)bf16r(W1[k * HID + col]);
            }
            w1r[hb][kk] = v;
        }

    // biases indexed by this lane's physical h = nq*32 + q*8 + hb*4 + r
    f32x4 b0q[2], b1q[2];
    for (int hb = 0; hb < 2; ++hb)
        for (int r = 0; r < 4; ++r) {
            const int h = nq * 32 + q * 8 + hb * 4 + r;
            b0q[hb][r] = b0[h];
            b1q[hb][r] = b1[h];
        }
    // L2 A-frag: A[m][k] = (m==0) ? W2[nq*32 + q*8 + k_e] : 0.
    // e enumerates hb*4+r in physical order 0..7, so W2 index is linear.
    bf16x8 w2f;
    #pragma unroll
    for (int e = 0; e < 8; ++e)
        w2f[e] = (cl == 0) ? (short)bf16r(W2[nq * 32 + q * 8 + e]) : (short)0;
    const float bias2 = b2[0];

    // ---- shallow prefetch: fe/x for the first tile (3 regs) ----
    int t = blockIdx.x;
    float  feA;
    float2 xvA = {0.f, 0.f};
    {
        const int gp = t * M_IT + p;
        feA = emb[gp];
        if (s == 0) xvA = *(const float2*)(x + 2 * gp);
    }

    __syncthreads();   // A0 zeroing visible before first build

    for (; t < TILES; t += gridDim.x) {
        const int base = t * M_IT;

        // ---- stage inputs into A0 (gathers start immediately: feA ready) --
        {
            const int e1 = (int)feA;
            const int e2 = (e1 + 1 < NUMEMB) ? e1 + 1 : NUMEMB - 1;
            const float r = feA - (float)e1;
            const float4* p1 = (const float4*)(em_table + e1 * 32 + s * 8);
            const float4* p2 = (const float4*)(em_table + e2 * 32 + s * 8);
            const float4 a0v = p1[0], a1v = p1[1];
            const float4 c0v = p2[0], c1v = p2[1];
            uint4 d;
            d.x = pk2(a0v.x + (c0v.x - a0v.x) * r, a0v.y + (c0v.y - a0v.y) * r);
            d.y = pk2(a0v.z + (c0v.z - a0v.z) * r, a0v.w + (c0v.w - a0v.w) * r);
            d.z = pk2(a1v.x + (c1v.x - a1v.x) * r, a1v.y + (c1v.y - a1v.y) * r);
            d.w = pk2(a1v.z + (c1v.z - a1v.z) * r, a1v.w + (c1v.w - a1v.w) * r);
            *(uint4*)&A0[p * A0S + s * 8] = d;
            if (s == 0) *(unsigned*)&A0[p * A0S + 32] = pk2(xvA.x, xvA.y);
        }
        __syncthreads();

        // ---- layer 0 (transposed, permuted cols): bias rides C operand ----
        f32x4 acc[4][2];   // [pb][hb]
        #pragma unroll
        for (int pb = 0; pb < 4; ++pb) {
            const bf16x8 bf0 = *(const bf16x8*)&A0[(pb * 16 + cl) * A0S + q * 8];
            const bf16x8 bf1 = *(const bf16x8*)&A0[(pb * 16 + cl) * A0S + 32 + q * 8];
            #pragma unroll
            for (int hb = 0; hb < 2; ++hb) {
                f32x4 a = __builtin_amdgcn_mfma_f32_16x16x32_bf16(
                    w0t[hb][0], bf0, b0q[hb], 0, 0, 0);
                acc[pb][hb] = __builtin_amdgcn_mfma_f32_16x16x32_bf16(
                    w0t[hb][1], bf1, a, 0, 0, 0);
            }
        }

        // prefetch fe/x for next tile (3 regs live across L1 only)
        {
            int t1 = t + gridDim.x; if (t1 >= TILES) t1 = t;
            const int gp = t1 * M_IT + p;
            feA = emb[gp];
            if (s == 0) xvA = *(const float2*)(x + 2 * gp);
        }

        // epi0: clamp fused into cvt (pk2c); straight to H0 (no own[]).
        #pragma unroll
        for (int pb = 0; pb < 4; ++pb) {
            const f32x4 v0 = acc[pb][0], v1 = acc[pb][1];
            uint4 w;
            w.x = pk2c(v0[0], v0[1]);
            w.y = pk2c(v0[2], v0[3]);
            w.z = pk2c(v1[0], v1[1]);
            w.w = pk2c(v1[2], v1[3]);
            *(uint4*)&H0[(pb * 16 + cl) * H0S + nq * 32 + q * 8] = w;
        }
        __syncthreads();

        // ---- layer 1: all kt from LDS; bias rides C at kk==0 (literal) ----
        #pragma unroll
        for (int kk = 0; kk < 4; ++kk) {
            const int kcol = (((nq + kk) & 3) << 5) + q * 8;  // runtime addr
            #pragma unroll
            for (int pb = 0; pb < 4; ++pb) {
                bf16x8 bfrag = *(const bf16x8*)
                    &H0[(pb * 16 + cl) * H0S + kcol];
                #pragma unroll
                for (int hb = 0; hb < 2; ++hb)
                    acc[pb][hb] = __builtin_amdgcn_mfma_f32_16x16x32_bf16(
                        w1r[hb][kk], bfrag,
                        kk == 0 ? b1q[hb] : acc[pb][hb], 0, 0, 0);
            }
        }

        // ---- layer 2 via MFMA: clamped-h1 frag is the B operand; ----------
        // D[0][cl] (lanes q==0, reg 0) = dot over this wave's 32 hiddens.
        const f32x4 zero = {0.f, 0.f, 0.f, 0.f};
        #pragma unroll
        for (int pb = 0; pb < 4; ++pb) {
            const f32x4 v0 = acc[pb][0], v1 = acc[pb][1];
            uint4 w;
            w.x = pk2c(v0[0], v0[1]);
            w.y = pk2c(v0[2], v0[3]);
            w.z = pk2c(v1[0], v1[1]);
            w.w = pk2c(v1[2], v1[3]);
            bf16x8 hf;
            __builtin_memcpy(&hf, &w, 16);
            const f32x4 z4 = __builtin_amdgcn_mfma_f32_16x16x32_bf16(
                w2f, hf, zero, 0, 0, 0);
            if (q == 0)
                *(float*)((char*)A0 + (pb * 16 + cl) * 144 + 128 + nq * 4) = z4[0];
        }
        __syncthreads();

        if (tid < 64) {
            const float4 pv = *(const float4*)((const char*)A0 + tid * 144 + 128);
            const float zz = bias2 + pv.x + pv.y + pv.z + pv.w;
            out[base + tid] = __builtin_amdgcn_rcpf(1.f + __expf(-zz));
        }
        // hazards: A0[cols 0..33] rewrite (next stage) is 2 barriers after
        // L0 reads; H0 rewrite 2 barriers after L1 reads; PART (A0 cols
        // 64..71) write->read has bar3, read->next-write has bar1+bar2;
        // stage(t+1) writes cols 0..33 only, disjoint from out-read bytes.
    }
}

extern "C" void kernel_launch(void* const* d_in, const int* in_sizes, int n_in,
                              void* d_out, int out_size, void* d_ws, size_t ws_size,
                              hipStream_t stream) {
    const float* x   = (const float*)d_in[0];
    const float* emb = (const float*)d_in[1];
    const float* emt = (const float*)d_in[2];
    const float* W0  = (const float*)d_in[3];
    const float* b0  = (const float*)d_in[4];
    const float* W1  = (const float*)d_in[5];
    const float* b1  = (const float*)d_in[6];
    const float* W2  = (const float*)d_in[7];
    const float* b2  = (const float*)d_in[8];
    mlp_fused<<<NBLOCKS, 256, 0, stream>>>(x, emb, emt, W0, b0, W1, b1, W2, b2,
                                           (float*)d_out);
}

// Round 5
// 121.815 us; speedup vs baseline: 1.1388x; 1.1388x over previous
//
#include <hip/hip_runtime.h>
#include <hip/hip_bf16.h>

// Fused 34->128->128->1 MLP, bf16 MFMA, transposed GEMMs.
// R15 = R12's twice-verified no-own[] diet source, launch contract moved to
// the only rung that has ever allocated without spill: launch_bounds(256,3),
// grid 768 (3 blocks/CU).
// R14 post-mortem: own[] + diet + (256,3) produced NaN — same source logic
// passed at (256,6) in R11, so the failing cell is allocation-specific
// (pk2c inline asm under mixed VGPR/AGPR pressure suspected). own[] only
// saves 4 ds_read_b128/wave-tile; dropped permanently.
// Model update: CSV VGPR_Count is ARCH VGPRs only — R10's "68" carried
// ~64 AGPRs of weights besides; liveness-vs-budget math must use totals.
// Reliable signals: WRITE_SIZE==3906KB <=> no spill; (256,3) <=> clean alloc.
// Diet (kept, verified correct at R11/R12/R13, absmax 0.00390625 stable):
//  - clamp fused into v_cvt_pk_bf16_f32 clamp (pk2c): -64 v_med3/wave-tile
//  - L2 as MFMA (W2 in A-frag row 0): kills 64-op VALU dot + 16-row PART
//    reduce; PART -> 4 floats/pt aliased into A0 cols 64..71 (LDS 26624B)
//  - biases ride first MFMA's C operand: -64 acc-init movs
//  - no own[]: L1 kk=0 reads H0 like kk>=1 (+4 ds_read_b128)
//  - w1r rotation: literal register indices in L1 (anti-scratch rule)
// R8a recap: physical hidden h = nq*32 + q*8 + hb*4 + r at MFMA position
// (nq,hb,q,r); L0 C/D frag == L1 B frag layout.
// Evidence trail: R6 -ds_bpermute 115->80; R7 transpose 80->72; R11-R14:
// every rung above 3 blocks/CU spilled (~14.5MB scratch, 77-78us) or
// miscompiled; spill >> occupancy for this kernel.

using bf16x8 = __attribute__((ext_vector_type(8))) short;   // 8 bf16 = 4 VGPRs
using f32x4  = __attribute__((ext_vector_type(4))) float;   // MFMA C/D

#define NPTS    1000000
#define NUMEMB  6572
#define HID     128
#define M_IT    64          // points per block-iteration
#define A0S     72          // A0 row stride in bf16 (144B, 16B-aligned rows)
#define H0S     136         // H0 row stride in bf16 (272B, 16B-aligned rows)
#define TILES   (NPTS / M_IT)   // 15625 exactly
#define NBLOCKS 768         // 3 blocks/CU on 256 CUs (proven non-spill rung)

__device__ __forceinline__ unsigned short bf16r(float f) {
    unsigned u;
    __builtin_memcpy(&u, &f, 4);
    u = (u + 0x7fffu + ((u >> 16) & 1u)) >> 16;
    return (unsigned short)u;
}
__device__ __forceinline__ unsigned pk2(float a, float b) {
    // packed RNE f32x2 -> bf16x2 (v_cvt_pk_bf16_f32 on gfx950)
    float2 f2; f2.x = a; f2.y = b;
    __hip_bfloat162 h = __float22bfloat162_rn(f2);
    unsigned u;
    __builtin_memcpy(&u, &h, 4);
    return u;
}
__device__ __forceinline__ unsigned pk2c(float a, float b) {
    // packed cvt with VOP3 clamp: result clamped to [0,1] — fuses clamp01
    unsigned r;
    asm("v_cvt_pk_bf16_f32 %0, %1, %2 clamp" : "=v"(r) : "v"(a), "v"(b));
    return r;
}

__global__ __launch_bounds__(256, 3)
void mlp_fused(const float* __restrict__ x,
               const float* __restrict__ emb,
               const float* __restrict__ em_table,
               const float* __restrict__ W0, const float* __restrict__ b0,
               const float* __restrict__ W1, const float* __restrict__ b1,
               const float* __restrict__ W2, const float* __restrict__ b2,
               float* __restrict__ out)
{
    __shared__ __align__(16) unsigned short A0[M_IT * A0S];  // bf16 [pt][in]
    __shared__ __align__(16) unsigned short H0[M_IT * H0S];  // bf16 [pt][hperm]
    // PART[p][w] aliased into A0 bytes p*144 + 128 + w*4 (cols 64..71,
    // never accessed as A0: reads span cols <=63, writes cols <=33).

    const int tid  = threadIdx.x;
    const int lane = tid & 63;
    const int nq   = tid >> 6;   // wave's physical hidden block [nq*32,+32)
    const int q    = lane >> 4;  // quad within wave
    const int cl   = lane & 15;
    const int p    = tid >> 2;   // staging: point within tile
    const int s    = tid & 3;    // staging: 8-dim segment of embedding

    // zero A0 once (cols 34..63 stay zero forever; build overwrites 0..33)
    for (int i = tid; i < M_IT * A0S; i += 256) A0[i] = 0;

    // ---- one-time: weight A-fragments (permuted cols) into registers ----
    // A-frag lane (q,cl) holds A[m=cl][k=q*8+e]. Permuted physical hidden
    // for column m within block (nq,hb): h = nq*32 + (m>>2)*8 + hb*4 + (m&3).
    const int hcol = nq * 32 + (cl >> 2) * 8 + (cl & 3);  // + hb*4
    // W0 logical row k: k<32 -> em row 2+k ; k==32 -> x row 0 ; k==33 -> 1.
    bf16x8 w0t[2][2];   // [hb][kt]
    for (int hb = 0; hb < 2; ++hb)
        for (int kt = 0; kt < 2; ++kt) {
            const int col = hcol + hb * 4;
            bf16x8 v;
            #pragma unroll
            for (int e = 0; e < 8; ++e) {
                const int k = kt * 32 + q * 8 + e;
                float val = 0.f;
                if (k < 32)       val = W0[(2 + k) * HID + col];
                else if (k == 32) val = W0[0 * HID + col];
                else if (k == 33) val = W0[1 * HID + col];
                v[e] = (short)bf16r(val);
            }
            w0t[hb][kt] = v;
        }

    // W1 ROTATED: w1r[hb][kk] holds rows kphys = ((nq+kk)&3)*32 + q*8 + e
    bf16x8 w1r[2][4];   // [hb][kk]
    for (int hb = 0; hb < 2; ++hb)
        for (int kk = 0; kk < 4; ++kk) {
            const int kt  = (nq + kk) & 3;
            const int col = hcol + hb * 4;
            bf16x8 v;
            #pragma unroll
            for (int e = 0; e < 8; ++e) {
                const int k = kt * 32 + q * 8 + e;
                v[e] = (short)bf16r(W1[k * HID + col]);
            }
            w1r[hb][kk] = v;
        }

    // biases indexed by this lane's physical h = nq*32 + q*8 + hb*4 + r
    f32x4 b0q[2], b1q[2];
    for (int hb = 0; hb < 2; ++hb)
        for (int r = 0; r < 4; ++r) {
            const int h = nq * 32 + q * 8 + hb * 4 + r;
            b0q[hb][r] = b0[h];
            b1q[hb][r] = b1[h];
        }
    // L2 A-frag: A[m][k] = (m==0) ? W2[nq*32 + q*8 + k_e] : 0.
    // e enumerates hb*4+r in physical order 0..7, so W2 index is linear.
    bf16x8 w2f;
    #pragma unroll
    for (int e = 0; e < 8; ++e)
        w2f[e] = (cl == 0) ? (short)bf16r(W2[nq * 32 + q * 8 + e]) : (short)0;
    const float bias2 = b2[0];

    // ---- shallow prefetch: fe/x for the first tile (3 regs) ----
    int t = blockIdx.x;
    float  feA;
    float2 xvA = {0.f, 0.f};
    {
        const int gp = t * M_IT + p;
        feA = emb[gp];
        if (s == 0) xvA = *(const float2*)(x + 2 * gp);
    }

    __syncthreads();   // A0 zeroing visible before first build

    for (; t < TILES; t += gridDim.x) {
        const int base = t * M_IT;

        // ---- stage inputs into A0 (gathers start immediately: feA ready) --
        {
            const int e1 = (int)feA;
            const int e2 = (e1 + 1 < NUMEMB) ? e1 + 1 : NUMEMB - 1;
            const float r = feA - (float)e1;
            const float4* p1 = (const float4*)(em_table + e1 * 32 + s * 8);
            const float4* p2 = (const float4*)(em_table + e2 * 32 + s * 8);
            const float4 a0v = p1[0], a1v = p1[1];
            const float4 c0v = p2[0], c1v = p2[1];
            uint4 d;
            d.x = pk2(a0v.x + (c0v.x - a0v.x) * r, a0v.y + (c0v.y - a0v.y) * r);
            d.y = pk2(a0v.z + (c0v.z - a0v.z) * r, a0v.w + (c0v.w - a0v.w) * r);
            d.z = pk2(a1v.x + (c1v.x - a1v.x) * r, a1v.y + (c1v.y - a1v.y) * r);
            d.w = pk2(a1v.z + (c1v.z - a1v.z) * r, a1v.w + (c1v.w - a1v.w) * r);
            *(uint4*)&A0[p * A0S + s * 8] = d;
            if (s == 0) *(unsigned*)&A0[p * A0S + 32] = pk2(xvA.x, xvA.y);
        }
        __syncthreads();

        // ---- layer 0 (transposed, permuted cols): bias rides C operand ----
        f32x4 acc[4][2];   // [pb][hb]
        #pragma unroll
        for (int pb = 0; pb < 4; ++pb) {
            const bf16x8 bf0 = *(const bf16x8*)&A0[(pb * 16 + cl) * A0S + q * 8];
            const bf16x8 bf1 = *(const bf16x8*)&A0[(pb * 16 + cl) * A0S + 32 + q * 8];
            #pragma unroll
            for (int hb = 0; hb < 2; ++hb) {
                f32x4 a = __builtin_amdgcn_mfma_f32_16x16x32_bf16(
                    w0t[hb][0], bf0, b0q[hb], 0, 0, 0);
                acc[pb][hb] = __builtin_amdgcn_mfma_f32_16x16x32_bf16(
                    w0t[hb][1], bf1, a, 0, 0, 0);
            }
        }

        // prefetch fe/x for next tile (3 regs live across L1 only)
        {
            int t1 = t + gridDim.x; if (t1 >= TILES) t1 = t;
            const int gp = t1 * M_IT + p;
            feA = emb[gp];
            if (s == 0) xvA = *(const float2*)(x + 2 * gp);
        }

        // epi0: clamp fused into cvt (pk2c); straight to H0 (no own[]).
        #pragma unroll
        for (int pb = 0; pb < 4; ++pb) {
            const f32x4 v0 = acc[pb][0], v1 = acc[pb][1];
            uint4 w;
            w.x = pk2c(v0[0], v0[1]);
            w.y = pk2c(v0[2], v0[3]);
            w.z = pk2c(v1[0], v1[1]);
            w.w = pk2c(v1[2], v1[3]);
            *(uint4*)&H0[(pb * 16 + cl) * H0S + nq * 32 + q * 8] = w;
        }
        __syncthreads();

        // ---- layer 1: all kt from LDS; bias rides C at kk==0 (literal) ----
        #pragma unroll
        for (int kk = 0; kk < 4; ++kk) {
            const int kcol = (((nq + kk) & 3) << 5) + q * 8;  // runtime addr
            #pragma unroll
            for (int pb = 0; pb < 4; ++pb) {
                bf16x8 bfrag = *(const bf16x8*)
                    &H0[(pb * 16 + cl) * H0S + kcol];
                #pragma unroll
                for (int hb = 0; hb < 2; ++hb)
                    acc[pb][hb] = __builtin_amdgcn_mfma_f32_16x16x32_bf16(
                        w1r[hb][kk], bfrag,
                        kk == 0 ? b1q[hb] : acc[pb][hb], 0, 0, 0);
            }
        }

        // ---- layer 2 via MFMA: clamped-h1 frag is the B operand; ----------
        // D[0][cl] (lanes q==0, reg 0) = dot over this wave's 32 hiddens.
        const f32x4 zero = {0.f, 0.f, 0.f, 0.f};
        #pragma unroll
        for (int pb = 0; pb < 4; ++pb) {
            const f32x4 v0 = acc[pb][0], v1 = acc[pb][1];
            uint4 w;
            w.x = pk2c(v0[0], v0[1]);
            w.y = pk2c(v0[2], v0[3]);
            w.z = pk2c(v1[0], v1[1]);
            w.w = pk2c(v1[2], v1[3]);
            bf16x8 hf;
            __builtin_memcpy(&hf, &w, 16);
            const f32x4 z4 = __builtin_amdgcn_mfma_f32_16x16x32_bf16(
                w2f, hf, zero, 0, 0, 0);
            if (q == 0)
                *(float*)((char*)A0 + (pb * 16 + cl) * 144 + 128 + nq * 4) = z4[0];
        }
        __syncthreads();

        if (tid < 64) {
            const float4 pv = *(const float4*)((const char*)A0 + tid * 144 + 128);
            const float zz = bias2 + pv.x + pv.y + pv.z + pv.w;
            out[base + tid] = __builtin_amdgcn_rcpf(1.f + __expf(-zz));
        }
        // hazards: A0[cols 0..33] rewrite (next stage) is 2 barriers after
        // L0 reads; H0 rewrite 2 barriers after L1 reads; PART (A0 cols
        // 64..71) write->read has bar3, read->next-write has bar1+bar2;
        // stage(t+1) writes cols 0..33 only, disjoint from out-read bytes.
    }
}

extern "C" void kernel_launch(void* const* d_in, const int* in_sizes, int n_in,
                              void* d_out, int out_size, void* d_ws, size_t ws_size,
                              hipStream_t stream) {
    const float* x   = (const float*)d_in[0];
    const float* emb = (const float*)d_in[1];
    const float* emt = (const float*)d_in[2];
    const float* W0  = (const float*)d_in[3];
    const float* b0  = (const float*)d_in[4];
    const float* W1  = (const float*)d_in[5];
    const float* b1  = (const float*)d_in[6];
    const float* W2  = (const float*)d_in[7];
    const float* b2  = (const float*)d_in[8];
    mlp_fused<<<NBLOCKS, 256, 0, stream>>>(x, emb, emt, W0, b0, W1, b1, W2, b2,
                                           (float*)d_out);
}